// Round 1
// baseline (83.965 us; speedup 1.0000x reference)
//
#include <hip/hip_runtime.h>

// PatchChamferDistance: B=32, G=64, P=256, D=3  ->  BG=2048 patches.
// per patch: dist2[i][j] = ||p_i||^2 + ||t_j||^2 - 2 p_i . t_j  (clamped >= 0)
// out = mean over patches of ( mean_i min_j dist2 + mean_j min_i dist2 )
//
// Trick: min_j (pn + tn_j - 2 p.t_j) = pn + min_j (tn_j - 2 p.t_j).
// Pack points in LDS as float4(-2x, -2y, -2z, ||.||^2): inner loop is
// 3 FMA + 1 min per pair, with the norm as FMA init.

#define NPATCH 2048
#define NPTS   256

__global__ __launch_bounds__(128) void chamfer_patch_kernel(
    const float* __restrict__ pred,
    const float* __restrict__ tgt,
    float* __restrict__ partial)
{
    __shared__ float4 pPk[NPTS];   // packed pred points
    __shared__ float4 tPk[NPTS];   // packed target points
    __shared__ float red[2];

    const int patch = blockIdx.x;
    const int tid   = threadIdx.x;
    const float* __restrict__ pb = pred + (size_t)patch * (NPTS * 3);
    const float* __restrict__ tb = tgt  + (size_t)patch * (NPTS * 3);

    // Each of the 128 threads packs 2 points from each array.
    #pragma unroll
    for (int q = 0; q < 2; ++q) {
        const int p = tid * 2 + q;
        float x = pb[3 * p + 0];
        float y = pb[3 * p + 1];
        float z = pb[3 * p + 2];
        pPk[p] = make_float4(-2.0f * x, -2.0f * y, -2.0f * z,
                             x * x + y * y + z * z);
        x = tb[3 * p + 0];
        y = tb[3 * p + 1];
        z = tb[3 * p + 2];
        tPk[p] = make_float4(-2.0f * x, -2.0f * y, -2.0f * z,
                             x * x + y * y + z * z);
    }
    __syncthreads();

    const int wave = tid >> 6;   // 0: forward (pred queries), 1: backward
    const int lane = tid & 63;

    float qx[4], qy[4], qz[4], qn[4], m[4];
    float s = 0.0f;

    if (wave == 0) {
        // forward: queries are pred points, iterate over packed targets
        #pragma unroll
        for (int q = 0; q < 4; ++q) {
            const float4 v = pPk[lane + 64 * q];
            qx[q] = -0.5f * v.x;
            qy[q] = -0.5f * v.y;
            qz[q] = -0.5f * v.z;
            qn[q] = v.w;
            m[q]  = 1e30f;
        }
        #pragma unroll 4
        for (int j = 0; j < NPTS; ++j) {
            const float4 t = tPk[j];
            #pragma unroll
            for (int q = 0; q < 4; ++q) {
                float d = fmaf(qx[q], t.x, t.w);
                d = fmaf(qy[q], t.y, d);
                d = fmaf(qz[q], t.z, d);
                m[q] = fminf(m[q], d);
            }
        }
        #pragma unroll
        for (int q = 0; q < 4; ++q) s += fmaxf(qn[q] + m[q], 0.0f);
    } else {
        // backward: queries are target points, iterate over packed preds
        #pragma unroll
        for (int q = 0; q < 4; ++q) {
            const float4 v = tPk[lane + 64 * q];
            qx[q] = -0.5f * v.x;
            qy[q] = -0.5f * v.y;
            qz[q] = -0.5f * v.z;
            qn[q] = v.w;
            m[q]  = 1e30f;
        }
        #pragma unroll 4
        for (int j = 0; j < NPTS; ++j) {
            const float4 t = pPk[j];
            #pragma unroll
            for (int q = 0; q < 4; ++q) {
                float d = fmaf(qx[q], t.x, t.w);
                d = fmaf(qy[q], t.y, d);
                d = fmaf(qz[q], t.z, d);
                m[q] = fminf(m[q], d);
            }
        }
        #pragma unroll
        for (int q = 0; q < 4; ++q) s += fmaxf(qn[q] + m[q], 0.0f);
    }

    // wave-level sum (64 lanes)
    #pragma unroll
    for (int off = 32; off > 0; off >>= 1)
        s += __shfl_down(s, off, 64);
    if (lane == 0) red[wave] = s;
    __syncthreads();
    if (tid == 0) partial[patch] = red[0] + red[1];
}

__global__ __launch_bounds__(256) void chamfer_reduce_kernel(
    const float* __restrict__ partial,
    float* __restrict__ out)
{
    __shared__ float red[4];
    const int tid = threadIdx.x;
    float s = 0.0f;
    #pragma unroll
    for (int i = tid; i < NPATCH; i += 256) s += partial[i];
    #pragma unroll
    for (int off = 32; off > 0; off >>= 1)
        s += __shfl_down(s, off, 64);
    if ((tid & 63) == 0) red[tid >> 6] = s;
    __syncthreads();
    if (tid == 0)
        out[0] = (red[0] + red[1] + red[2] + red[3]) *
                 (1.0f / ((float)NPTS * (float)NPATCH));
}

extern "C" void kernel_launch(void* const* d_in, const int* in_sizes, int n_in,
                              void* d_out, int out_size, void* d_ws, size_t ws_size,
                              hipStream_t stream) {
    const float* pred = (const float*)d_in[0];
    const float* tgt  = (const float*)d_in[1];
    float* partial    = (float*)d_ws;      // 2048 floats = 8 KB scratch
    float* out        = (float*)d_out;

    chamfer_patch_kernel<<<NPATCH, 128, 0, stream>>>(pred, tgt, partial);
    chamfer_reduce_kernel<<<1, 256, 0, stream>>>(partial, out);
}